// Round 11
// baseline (161.982 us; speedup 1.0000x reference)
//
#include <hip/hip_runtime.h>

typedef unsigned int uint;
typedef unsigned short ushort;
typedef __attribute__((ext_vector_type(8))) short short8v;
typedef __attribute__((ext_vector_type(4))) float f32x4;
typedef __attribute__((ext_vector_type(4))) uint uint4v;
typedef __attribute__((ext_vector_type(4))) int int4v;

#define D 128
#define LDH 136      // LDS row stride in ushorts (272 B, b128-aligned)
#define NPB 64       // nodes per coarse bucket == MLP tile rows (power of 2)
#define PSHIFT 26    // pairs pack: local_dst(6b) << 26 | src(26b)  (needs N < 2^26)
#define NBLK 256     // histogram/scatter blocks (fixed partition)
#define MAXNC 4096   // max coarse buckets (N <= 262144)
#define SRTCAP 4096  // per-bucket sorted-src capacity (avg 1024; 16 KB fits in S union)

// ---------- edge-index dtype hedge (int64 vs int32), wave-uniform ----------
__device__ __forceinline__ bool ei_is64(const int* ei32) {
    return ((ei32[1] | ei32[3] | ei32[5] | ei32[7]) == 0);
}
__device__ __forceinline__ float b2f(ushort u) { return __uint_as_float((uint)u << 16); }
__device__ __forceinline__ ushort f2b(float f) {   // RNE
    uint a = __float_as_uint(f);
    return (ushort)((a + 0x7fffu + ((a >> 16) & 1u)) >> 16);
}
__device__ __forceinline__ uint f2b2(float lo, float hi) {   // pack 2 bf16
    return (uint)f2b(lo) | ((uint)f2b(hi) << 16);
}

// ---- prep: coarse histogram -> TRANSPOSED harr[c][b]  +  W->bf16^T ----
__global__ __launch_bounds__(256) void gin_prep(
    const void* __restrict__ ei_raw, int* __restrict__ harr, int NC, int E,
    const float* __restrict__ W1, const float* __restrict__ W2,
    ushort* __restrict__ w1t, ushort* __restrict__ w2t)
{
    __shared__ int h[MAXNC];
    int bid = blockIdx.x;
    if (bid < NBLK) {
        for (int i = threadIdx.x; i < NC; i += 256) h[i] = 0;
        __syncthreads();
        const int* ei32 = (const int*)ei_raw;
        const long long* ei64 = (const long long*)ei_raw;
        const bool is64 = ei_is64(ei32);
        for (int e = bid * 256 + threadIdx.x; e < E; e += 256 * NBLK) {
            int dst = is64 ? (int)ei64[e] : ei32[e];
            atomicAdd(&h[dst >> 6], 1);   // LDS atomic; NPB == 64
        }
        __syncthreads();
        for (int i = threadIdx.x; i < NC; i += 256)
            __builtin_nontemporal_store(h[i], &harr[(size_t)i * NBLK + bid]);
    } else {
        int idx = (bid - NBLK) * 256 + threadIdx.x;   // [0, 2*128*128)
        int which = idx >> 14;
        int rem   = idx & 16383;                      // n*128 + k
        int k = rem & 127, n = rem >> 7;
        const float* W = which ? W2 : W1;
        ushort* WT = which ? w2t : w1t;
        WT[rem] = f2b(W[k * D + n]);                  // WT[n][k] = W[k][n]
    }
}

// ---- column scan, one wave per column: harr[c][0..255] -> exclusive; tot[c] ----
__global__ __launch_bounds__(512) void gin_colsum(
    int* __restrict__ harr, int* __restrict__ tot, int NC)
{
    int wv   = (blockIdx.x * 512 + threadIdx.x) >> 6;   // global wave id = column
    int lane = threadIdx.x & 63;
    if (wv >= NC) return;
    int4v* col = (int4v*)(harr + (size_t)wv * NBLK);
    int4v v = __builtin_nontemporal_load(col + lane);   // coalesced 16 B/lane
    int s = v.x + v.y + v.z + v.w;
    int inc = s;
    #pragma unroll
    for (int d = 1; d < 64; d <<= 1) {
        int t = __shfl_up(inc, d, 64);
        if (lane >= d) inc += t;
    }
    int excl = inc - s;
    int4v o;
    o.x = excl; o.y = excl + v.x; o.z = o.y + v.y; o.w = o.z + v.z;
    __builtin_nontemporal_store(o, col + lane);
    if (lane == 63) __builtin_nontemporal_store(inc, &tot[wv]);
}

// ---- coarse scatter (blocks < NBLK) + x->bf16 convert (remaining blocks) ----
// Scatter blocks scan tot[] in LDS (identical, parallel); block 0 publishes coff.
// All cross-XCD-consumed outputs (pairs, xb, coff) use non-temporal stores.
__global__ __launch_bounds__(256) void gin_cscatter(
    const void* __restrict__ ei_raw, const int* __restrict__ harr,
    const int* __restrict__ tot, int* __restrict__ coff,
    uint* __restrict__ pairs, int NC, int E,
    const float4* __restrict__ x4, uint4v* __restrict__ xb16, int n8)
{
    __shared__ int sc[MAXNC + 1];
    __shared__ int part[256];
    const int tid = threadIdx.x;
    if (blockIdx.x >= NBLK) {            // x -> bf16 conversion blocks (8 floats/thread)
        int i = (blockIdx.x - NBLK) * 256 + tid;
        if (i < n8) {
            float4 a = x4[i * 2 + 0];
            float4 b = x4[i * 2 + 1];
            uint4v o;
            o.x = f2b2(a.x, a.y); o.y = f2b2(a.z, a.w);
            o.z = f2b2(b.x, b.y); o.w = f2b2(b.z, b.w);
            __builtin_nontemporal_store(o, xb16 + i);
        }
        return;
    }
    const int CH = (NC + 1 + 255) >> 8;
    const int base = tid * CH;
    int lsum = 0;
    for (int j = 0; j < CH; ++j) {
        int idx = base + j;
        if (idx < NC) lsum += tot[idx];
    }
    part[tid] = lsum;
    __syncthreads();
    for (int d = 1; d < 256; d <<= 1) {
        int t = (tid >= d) ? part[tid - d] : 0;
        __syncthreads();
        part[tid] += t;
        __syncthreads();
    }
    int run = part[tid] - lsum;   // exclusive over chunks
    for (int j = 0; j < CH; ++j) {
        int idx = base + j;
        if (idx <= NC) { sc[idx] = run; if (idx < NC) run += tot[idx]; }
    }
    __syncthreads();
    if (blockIdx.x == 0)
        for (int i = tid; i <= NC; i += 256)
            __builtin_nontemporal_store(sc[i], &coff[i]);
    for (int i = tid; i < NC; i += 256)
        sc[i] += harr[(size_t)i * NBLK + blockIdx.x];     // transposed read
    __syncthreads();
    const int* ei32 = (const int*)ei_raw;
    const long long* ei64 = (const long long*)ei_raw;
    const bool is64 = ei_is64(ei32);
    for (int e = blockIdx.x * 256 + tid; e < E; e += 256 * NBLK) {
        int dst, src;
        if (is64) { dst = (int)ei64[e]; src = (int)ei64[E + e]; }
        else      { dst = ei32[e];      src = ei32[E + e]; }
        int c = dst >> 6;
        int p = atomicAdd(&sc[c], 1);   // LDS atomic
        uint pv = ((uint)(dst & (NPB - 1)) << PSHIFT) | (uint)src;
        __builtin_nontemporal_store(pv, &pairs[p]);
    }
}

// ---------------- 8-wave MFMA MLP over S (64 rows), wave w -> n-tile w ----------------
// mfma_f32_16x16x32_bf16: A row=l&15, k=(l>>4)*8+j; B col=l&15; C/D col=l&15,
// row=(l>>4)*4+reg (m89-verified).
__device__ __forceinline__ void mlp8(
    ushort* S, const ushort* __restrict__ w1t, const ushort* __restrict__ w2t,
    const float* __restrict__ b1, const float* __restrict__ b2,
    float* __restrict__ out, long long n0, int N, int tid)
{
    const int w   = tid >> 6;     // wave 0..7 -> output cols [w*16, w*16+16)
    const int l   = tid & 63;
    const int c16 = l & 15;
    const int g   = l >> 4;

    f32x4 acc[4];
    {
        float bv = b1[w * 16 + c16];
        #pragma unroll
        for (int m = 0; m < 4; ++m) acc[m] = (f32x4){bv, bv, bv, bv};
    }
    #pragma unroll
    for (int ks = 0; ks < 4; ++ks) {
        short8v bB = *(const short8v*)&w1t[(w * 16 + c16) * D + ks * 32 + g * 8];
        #pragma unroll
        for (int m = 0; m < 4; ++m) {
            short8v a = *(const short8v*)&S[(m * 16 + c16) * LDH + ks * 32 + g * 8];
            acc[m] = __builtin_amdgcn_mfma_f32_16x16x32_bf16(a, bB, acc[m], 0, 0, 0);
        }
    }
    __syncthreads();   // all Z reads complete before H overwrite
    #pragma unroll
    for (int m = 0; m < 4; ++m)
        #pragma unroll
        for (int r = 0; r < 4; ++r)
            S[(m * 16 + g * 4 + r) * LDH + w * 16 + c16] = f2b(fmaxf(acc[m][r], 0.f));
    __syncthreads();
    {
        float bv = b2[w * 16 + c16];
        #pragma unroll
        for (int m = 0; m < 4; ++m) acc[m] = (f32x4){bv, bv, bv, bv};
    }
    #pragma unroll
    for (int ks = 0; ks < 4; ++ks) {
        short8v bB = *(const short8v*)&w2t[(w * 16 + c16) * D + ks * 32 + g * 8];
        #pragma unroll
        for (int m = 0; m < 4; ++m) {
            short8v a = *(const short8v*)&S[(m * 16 + c16) * LDH + ks * 32 + g * 8];
            acc[m] = __builtin_amdgcn_mfma_f32_16x16x32_bf16(a, bB, acc[m], 0, 0, 0);
        }
    }
    #pragma unroll
    for (int m = 0; m < 4; ++m)
        #pragma unroll
        for (int r = 0; r < 4; ++r) {
            long long row = n0 + m * 16 + g * 4 + r;
            if (row < N)
                __builtin_nontemporal_store(acc[m][r], &out[row * D + w * 16 + c16]);
        }
}

// ---- fused fine-sort + gather(regs) + MFMA MLP: one 512-thread block per bucket ----
// pairs staged in registers (1 nt global read); wave-0 shuffle scan (2 barriers);
// srt and S share one LDS union.
__global__ __launch_bounds__(512, 8) void gin_sg_mlp(
    const uint* __restrict__ pairs, const int* __restrict__ coff,
    const ushort* __restrict__ xb, const float* __restrict__ epsp,
    const ushort* __restrict__ w1t, const ushort* __restrict__ w2t,
    const float* __restrict__ b1, const float* __restrict__ b2,
    float* __restrict__ out, int N)
{
    __shared__ int4 U[(NPB * LDH * 2 + 15) / 16];   // 17408 B union
    int*    srt = (int*)U;                          // [SRTCAP] (16 KB)
    ushort* S   = (ushort*)U;                       // [NPB][LDH]
    __shared__ int hist[NPB], ex[NPB], cur[NPB];
    const int c = blockIdx.x;
    const int s = coff[c], e = coff[c + 1];
    const int size = e - s;
    const int tid = threadIdx.x;
    const float epsv = 1.0f + epsp[0];
    const long long nb = (long long)c * NPB;
    const ushort4* xr = (const ushort4*)xb;
    const int lane = tid & 31, grp = tid >> 5;   // 16 groups of 32 lanes

    if (size <= SRTCAP) {
        if (tid < NPB) { hist[tid] = 0; cur[tid] = 0; }
        uint pr[8]; int np = 0;
        #pragma unroll
        for (int k = 0; k < 8; ++k) {
            int i = tid + k * 512;
            if (i < size) { pr[k] = __builtin_nontemporal_load(&pairs[s + i]); np = k + 1; }
        }
        __syncthreads();
        #pragma unroll
        for (int k = 0; k < 8; ++k)
            if (k < np) atomicAdd(&hist[pr[k] >> PSHIFT], 1);
        __syncthreads();
        if (tid < 64) {                     // single-wave shuffle scan
            int v = hist[tid];
            int inc = v;
            #pragma unroll
            for (int d = 1; d < 64; d <<= 1) {
                int t = __shfl_up(inc, d, 64);
                if (tid >= d) inc += t;
            }
            ex[tid] = inc - v;              // exclusive
        }
        __syncthreads();
        #pragma unroll
        for (int k = 0; k < 8; ++k)
            if (k < np) {
                uint p = pr[k];
                int ld = p >> PSHIFT;
                int pos = atomicAdd(&cur[ld], 1);
                srt[ex[ld] + pos] = (int)(p & ((1u << PSHIFT) - 1u));
            }
        __syncthreads();
        // gather to registers: each group owns 4 nodes {grp, grp+16, grp+32, grp+48}
        float4 accv[4];
        #pragma unroll
        for (int q = 0; q < 4; ++q) {
            int nn = grp + q * 16;
            long long node = nb + nn;
            float4 acc = make_float4(0.f, 0.f, 0.f, 0.f);
            if (node < N) {
                ushort4 rs = xr[node * 32 + lane];
                acc.x = epsv * b2f(rs.x); acc.y = epsv * b2f(rs.y);
                acc.z = epsv * b2f(rs.z); acc.w = epsv * b2f(rs.w);
                int start = ex[nn];
                int deg   = hist[nn];
                int j = 0;
                for (; j + 8 <= deg; j += 8) {
                    int sx[8];
                    #pragma unroll
                    for (int u = 0; u < 8; ++u) sx[u] = srt[start + j + u];
                    ushort4 r[8];
                    #pragma unroll
                    for (int u = 0; u < 8; ++u) r[u] = xr[(long long)sx[u] * 32 + lane];
                    #pragma unroll
                    for (int u = 0; u < 8; ++u) {
                        acc.x += b2f(r[u].x); acc.y += b2f(r[u].y);
                        acc.z += b2f(r[u].z); acc.w += b2f(r[u].w);
                    }
                }
                for (; j < deg; ++j) {
                    int sx = srt[start + j];
                    ushort4 r = xr[(long long)sx * 32 + lane];
                    acc.x += b2f(r.x); acc.y += b2f(r.y);
                    acc.z += b2f(r.z); acc.w += b2f(r.w);
                }
            }
            accv[q] = acc;
        }
        __syncthreads();   // all srt reads done; safe to overwrite with S
        #pragma unroll
        for (int q = 0; q < 4; ++q) {
            int nn = grp + q * 16;
            ushort4 o;
            o.x = f2b(accv[q].x); o.y = f2b(accv[q].y);
            o.z = f2b(accv[q].z); o.w = f2b(accv[q].w);
            *(ushort4*)&S[nn * LDH + lane * 4] = o;
        }
        __syncthreads();
    } else {
        // oversized-bucket fallback (statistically never): per-node global scan.
        #pragma unroll
        for (int q = 0; q < 4; ++q) {
            int nn = grp + q * 16;
            long long node = nb + nn;
            float4 acc = make_float4(0.f, 0.f, 0.f, 0.f);
            if (node < N) {
                ushort4 rs = xr[node * 32 + lane];
                acc.x = epsv * b2f(rs.x); acc.y = epsv * b2f(rs.y);
                acc.z = epsv * b2f(rs.z); acc.w = epsv * b2f(rs.w);
                for (int i = 0; i < size; ++i) {
                    uint p = pairs[s + i];
                    if ((int)(p >> PSHIFT) == nn) {
                        long long sx = p & ((1u << PSHIFT) - 1u);
                        ushort4 r = xr[sx * 32 + lane];
                        acc.x += b2f(r.x); acc.y += b2f(r.y);
                        acc.z += b2f(r.z); acc.w += b2f(r.w);
                    }
                }
            }
            ushort4 o;
            o.x = f2b(acc.x); o.y = f2b(acc.y); o.z = f2b(acc.z); o.w = f2b(acc.w);
            *(ushort4*)&S[nn * LDH + lane * 4] = o;
        }
        __syncthreads();
    }
    mlp8(S, w1t, w2t, b1, b2, out, nb, N, tid);
}

extern "C" void kernel_launch(void* const* d_in, const int* in_sizes, int n_in,
                              void* d_out, int out_size, void* d_ws, size_t ws_size,
                              hipStream_t stream) {
    const float* x   = (const float*)d_in[0];
    const void*  ei  = d_in[1];
    const float* eps = (const float*)d_in[3];
    const float* W1  = (const float*)d_in[4];
    const float* b1  = (const float*)d_in[5];
    const float* W2  = (const float*)d_in[6];
    const float* b2  = (const float*)d_in[7];
    float* out = (float*)d_out;

    const int N = in_sizes[0] / D;   // 100000
    const int E = in_sizes[1] / 2;   // 1600000
    const int NC = (N + NPB - 1) / NPB;           // coarse buckets (1563 <= MAXNC)
    const int NCp = (NC + 1 + 255) & ~255;

    // ws: coff[NCp] tot[NCp] harr[NC*NBLK] pairs[E] | xb | w1t w2t
    int* coff   = (int*)d_ws;
    int* tot    = coff + NCp;
    int* harr   = tot + NCp;
    uint* pairs = (uint*)(harr + (size_t)NBLK * NC);
    size_t base   = ((size_t)2 * NCp + (size_t)NBLK * NC + (size_t)E) * sizeof(int);
    size_t xb_off = (base + 15) & ~(size_t)15;
    size_t w1_off = xb_off + (size_t)N * D * sizeof(ushort);
    size_t w2_off = w1_off + (size_t)D * D * sizeof(ushort);
    size_t need   = w2_off + (size_t)D * D * sizeof(ushort);

    if (ws_size < need || NC > MAXNC) return;   // cannot happen for this problem

    ushort* xb  = (ushort*)((char*)d_ws + xb_off);
    ushort* w1t = (ushort*)((char*)d_ws + w1_off);
    ushort* w2t = (ushort*)((char*)d_ws + w2_off);

    const int n8  = N * D / 8;                    // 16-B bf16 store groups
    const int nxb = (n8 + 255) / 256;
    gin_prep<<<NBLK + 128, 256, 0, stream>>>(ei, harr, NC, E, W1, W2, w1t, w2t);
    gin_colsum<<<(NC * 64 + 511) / 512, 512, 0, stream>>>(harr, tot, NC);
    gin_cscatter<<<NBLK + nxb, 256, 0, stream>>>(ei, harr, tot, coff, pairs, NC, E,
                                                 (const float4*)x, (uint4v*)xb, n8);
    gin_sg_mlp<<<NC, 512, 0, stream>>>(pairs, coff, xb, eps, w1t, w2t, b1, b2, out, N);
}

// Round 12
// 126.295 us; speedup vs baseline: 1.2826x; 1.2826x over previous
//
#include <hip/hip_runtime.h>

typedef unsigned int uint;
typedef unsigned short ushort;
typedef __attribute__((ext_vector_type(8))) short short8v;
typedef __attribute__((ext_vector_type(4))) float f32x4;
typedef __attribute__((ext_vector_type(4))) uint uint4v;

#define D 128
#define LDH 136      // LDS row stride in ushorts (272 B, b128-aligned)
#define NPB 64       // nodes per coarse bucket == MLP tile rows (power of 2)
#define PSHIFT 26    // pairs pack: local_dst(6b) << 26 | src(26b)  (needs N < 2^26)
#define NBLK 256     // histogram/scatter blocks (fixed partition)
#define MAXNC 4096   // max coarse buckets (N <= 262144)
#define REGCAP 2048  // register-staged pairs per block (8 x 256)

// ---------- edge-index dtype hedge (int64 vs int32), wave-uniform ----------
__device__ __forceinline__ bool ei_is64(const int* ei32) {
    return ((ei32[1] | ei32[3] | ei32[5] | ei32[7]) == 0);
}
__device__ __forceinline__ float b2f(ushort u) { return __uint_as_float((uint)u << 16); }
__device__ __forceinline__ ushort f2b(float f) {   // RNE
    uint a = __float_as_uint(f);
    return (ushort)((a + 0x7fffu + ((a >> 16) & 1u)) >> 16);
}
__device__ __forceinline__ uint f2b2(float lo, float hi) {   // pack 2 bf16
    return (uint)f2b(lo) | ((uint)f2b(hi) << 16);
}

// ---- prep: coarse histogram -> TRANSPOSED harr[c][b]  +  W->bf16^T ----
__global__ __launch_bounds__(256) void gin_prep(
    const void* __restrict__ ei_raw, int* __restrict__ harr, int NC, int E,
    const float* __restrict__ W1, const float* __restrict__ W2,
    ushort* __restrict__ w1t, ushort* __restrict__ w2t)
{
    __shared__ int h[MAXNC];
    int bid = blockIdx.x;
    if (bid < NBLK) {
        for (int i = threadIdx.x; i < NC; i += 256) h[i] = 0;
        __syncthreads();
        const int* ei32 = (const int*)ei_raw;
        const long long* ei64 = (const long long*)ei_raw;
        const bool is64 = ei_is64(ei32);
        for (int e = bid * 256 + threadIdx.x; e < E; e += 256 * NBLK) {
            int dst = is64 ? (int)ei64[e] : ei32[e];
            atomicAdd(&h[dst >> 6], 1);   // LDS atomic; NPB == 64
        }
        __syncthreads();
        for (int i = threadIdx.x; i < NC; i += 256)
            harr[(size_t)i * NBLK + bid] = h[i];          // transposed write
    } else {
        int idx = (bid - NBLK) * 256 + threadIdx.x;   // [0, 2*128*128)
        int which = idx >> 14;
        int rem   = idx & 16383;                      // n*128 + k
        int k = rem & 127, n = rem >> 7;
        const float* W = which ? W2 : W1;
        ushort* WT = which ? w2t : w1t;
        WT[rem] = f2b(W[k * D + n]);                  // WT[n][k] = W[k][n]
    }
}

// ---- column scan, one wave per column: harr[c][0..255] -> exclusive; tot[c] ----
__global__ __launch_bounds__(512) void gin_colsum(
    int* __restrict__ harr, int* __restrict__ tot, int NC)
{
    int wv   = (blockIdx.x * 512 + threadIdx.x) >> 6;   // global wave id = column
    int lane = threadIdx.x & 63;
    if (wv >= NC) return;
    int4* col = (int4*)(harr + (size_t)wv * NBLK);
    int4 v = col[lane];                       // coalesced 16 B/lane
    int s = v.x + v.y + v.z + v.w;
    int inc = s;
    #pragma unroll
    for (int d = 1; d < 64; d <<= 1) {
        int t = __shfl_up(inc, d, 64);
        if (lane >= d) inc += t;
    }
    int excl = inc - s;
    int4 o;
    o.x = excl; o.y = excl + v.x; o.z = o.y + v.y; o.w = o.z + v.z;
    col[lane] = o;
    if (lane == 63) tot[wv] = inc;
}

// ---- coarse scatter (blocks < NBLK) + x->bf16 convert (remaining blocks) ----
__global__ __launch_bounds__(256) void gin_cscatter(
    const void* __restrict__ ei_raw, const int* __restrict__ harr,
    const int* __restrict__ tot, int* __restrict__ coff,
    uint* __restrict__ pairs, int NC, int E,
    const float4* __restrict__ x4, uint4v* __restrict__ xb16, int n8)
{
    __shared__ int sc[MAXNC + 1];
    __shared__ int part[256];
    const int tid = threadIdx.x;
    if (blockIdx.x >= NBLK) {            // x -> bf16 conversion (8 floats/thread)
        int i = (blockIdx.x - NBLK) * 256 + tid;
        if (i < n8) {
            float4 a = x4[i * 2 + 0];
            float4 b = x4[i * 2 + 1];
            uint4v o;
            o.x = f2b2(a.x, a.y); o.y = f2b2(a.z, a.w);
            o.z = f2b2(b.x, b.y); o.w = f2b2(b.z, b.w);
            xb16[i] = o;
        }
        return;
    }
    const int CH = (NC + 1 + 255) >> 8;
    const int base = tid * CH;
    int lsum = 0;
    for (int j = 0; j < CH; ++j) {
        int idx = base + j;
        if (idx < NC) lsum += tot[idx];
    }
    part[tid] = lsum;
    __syncthreads();
    for (int d = 1; d < 256; d <<= 1) {
        int t = (tid >= d) ? part[tid - d] : 0;
        __syncthreads();
        part[tid] += t;
        __syncthreads();
    }
    int run = part[tid] - lsum;   // exclusive over chunks
    for (int j = 0; j < CH; ++j) {
        int idx = base + j;
        if (idx <= NC) { sc[idx] = run; if (idx < NC) run += tot[idx]; }
    }
    __syncthreads();
    if (blockIdx.x == 0)
        for (int i = tid; i <= NC; i += 256) coff[i] = sc[i];
    for (int i = tid; i < NC; i += 256)
        sc[i] += harr[(size_t)i * NBLK + blockIdx.x];     // transposed read
    __syncthreads();
    const int* ei32 = (const int*)ei_raw;
    const long long* ei64 = (const long long*)ei_raw;
    const bool is64 = ei_is64(ei32);
    for (int e = blockIdx.x * 256 + tid; e < E; e += 256 * NBLK) {
        int dst, src;
        if (is64) { dst = (int)ei64[e]; src = (int)ei64[E + e]; }
        else      { dst = ei32[e];      src = ei32[E + e]; }
        int c = dst >> 6;
        int p = atomicAdd(&sc[c], 1);   // LDS atomic
        pairs[p] = ((uint)(dst & (NPB - 1)) << PSHIFT) | (uint)src;
    }
}

// ------- 4-wave MFMA MLP over S (64 rows); wave w -> col-tiles {2w, 2w+1} -------
// mfma_f32_16x16x32_bf16: A row=l&15, k=(l>>4)*8+j; B col=l&15; C/D col=l&15,
// row=(l>>4)*4+reg (m89-verified).
__device__ __forceinline__ void mlp4(
    ushort* S, const ushort* __restrict__ w1t, const ushort* __restrict__ w2t,
    const float* __restrict__ b1, const float* __restrict__ b2,
    float* __restrict__ out, long long n0, int N, int tid)
{
    const int w   = tid >> 6;     // wave 0..3  -> n-tiles {2w, 2w+1}
    const int l   = tid & 63;
    const int c16 = l & 15;
    const int g   = l >> 4;
    const int n2a = 2 * w, n2b = 2 * w + 1;

    f32x4 acc[4][2];
    {
        float bva = b1[n2a * 16 + c16];
        float bvb = b1[n2b * 16 + c16];
        #pragma unroll
        for (int m = 0; m < 4; ++m) {
            acc[m][0] = (f32x4){bva, bva, bva, bva};
            acc[m][1] = (f32x4){bvb, bvb, bvb, bvb};
        }
    }
    #pragma unroll
    for (int ks = 0; ks < 4; ++ks) {
        short8v bA = *(const short8v*)&w1t[(n2a * 16 + c16) * D + ks * 32 + g * 8];
        short8v bB = *(const short8v*)&w1t[(n2b * 16 + c16) * D + ks * 32 + g * 8];
        #pragma unroll
        for (int m = 0; m < 4; ++m) {
            short8v a = *(const short8v*)&S[(m * 16 + c16) * LDH + ks * 32 + g * 8];
            acc[m][0] = __builtin_amdgcn_mfma_f32_16x16x32_bf16(a, bA, acc[m][0], 0, 0, 0);
            acc[m][1] = __builtin_amdgcn_mfma_f32_16x16x32_bf16(a, bB, acc[m][1], 0, 0, 0);
        }
    }
    __syncthreads();   // all Z reads complete before H overwrite
    #pragma unroll
    for (int m = 0; m < 4; ++m)
        #pragma unroll
        for (int ns = 0; ns < 2; ++ns) {
            int coln = (2 * w + ns) * 16 + c16;
            #pragma unroll
            for (int r = 0; r < 4; ++r)
                S[(m * 16 + g * 4 + r) * LDH + coln] = f2b(fmaxf(acc[m][ns][r], 0.f));
        }
    __syncthreads();
    {
        float bva = b2[n2a * 16 + c16];
        float bvb = b2[n2b * 16 + c16];
        #pragma unroll
        for (int m = 0; m < 4; ++m) {
            acc[m][0] = (f32x4){bva, bva, bva, bva};
            acc[m][1] = (f32x4){bvb, bvb, bvb, bvb};
        }
    }
    #pragma unroll
    for (int ks = 0; ks < 4; ++ks) {
        short8v bA = *(const short8v*)&w2t[(n2a * 16 + c16) * D + ks * 32 + g * 8];
        short8v bB = *(const short8v*)&w2t[(n2b * 16 + c16) * D + ks * 32 + g * 8];
        #pragma unroll
        for (int m = 0; m < 4; ++m) {
            short8v a = *(const short8v*)&S[(m * 16 + c16) * LDH + ks * 32 + g * 8];
            acc[m][0] = __builtin_amdgcn_mfma_f32_16x16x32_bf16(a, bA, acc[m][0], 0, 0, 0);
            acc[m][1] = __builtin_amdgcn_mfma_f32_16x16x32_bf16(a, bB, acc[m][1], 0, 0, 0);
        }
    }
    #pragma unroll
    for (int m = 0; m < 4; ++m)
        #pragma unroll
        for (int ns = 0; ns < 2; ++ns) {
            long long coln = (2 * w + ns) * 16 + c16;
            #pragma unroll
            for (int r = 0; r < 4; ++r) {
                long long row = n0 + m * 16 + g * 4 + r;
                if (row < N)
                    __builtin_nontemporal_store(acc[m][ns][r],
                                                &out[row * D + coln]);
            }
        }
}

// ---- fused fine-sort + gather(regs) + MFMA MLP: one 256-thread block per bucket ----
// All NC blocks co-resident (4 waves, 18.2 KB LDS, VGPR<=64 -> 8 blocks/CU).
__global__ __launch_bounds__(256, 8) void gin_sg_mlp(
    const uint* __restrict__ pairs, const int* __restrict__ coff,
    const ushort* __restrict__ xb, const float* __restrict__ epsp,
    const ushort* __restrict__ w1t, const ushort* __restrict__ w2t,
    const float* __restrict__ b1, const float* __restrict__ b2,
    float* __restrict__ out, int N)
{
    __shared__ int4 U[(NPB * LDH * 2 + 15) / 16];   // 17408 B union
    int*    srt = (int*)U;                          // [<=4096] (16 KB)
    ushort* S   = (ushort*)U;                       // [NPB][LDH]
    __shared__ int hist[NPB], ex[NPB], cur[NPB];
    const int c = blockIdx.x;
    const int s = coff[c], e = coff[c + 1];
    const int size = e - s;
    const int tid = threadIdx.x;
    const float epsv = 1.0f + epsp[0];
    const long long nb = (long long)c * NPB;
    const ushort4* xr = (const ushort4*)xb;
    const int lane = tid & 31, grp = tid >> 5;   // 8 groups of 32 lanes

    if (size <= REGCAP) {
        if (tid < NPB) { hist[tid] = 0; cur[tid] = 0; }
        uint pr[8]; int np = 0;
        #pragma unroll
        for (int k = 0; k < 8; ++k) {
            int i = tid + k * 256;
            if (i < size) { pr[k] = __builtin_nontemporal_load(&pairs[s + i]); np = k + 1; }
        }
        __syncthreads();
        #pragma unroll
        for (int k = 0; k < 8; ++k)
            if (k < np) atomicAdd(&hist[pr[k] >> PSHIFT], 1);
        __syncthreads();
        if (tid < 64) {                     // single-wave shuffle scan
            int v = hist[tid];
            int inc = v;
            #pragma unroll
            for (int d = 1; d < 64; d <<= 1) {
                int t = __shfl_up(inc, d, 64);
                if (tid >= d) inc += t;
            }
            ex[tid] = inc - v;              // exclusive
        }
        __syncthreads();
        #pragma unroll
        for (int k = 0; k < 8; ++k)
            if (k < np) {
                uint p = pr[k];
                int ld = p >> PSHIFT;
                int pos = atomicAdd(&cur[ld], 1);
                srt[ex[ld] + pos] = (int)(p & ((1u << PSHIFT) - 1u));
            }
        __syncthreads();
        // gather to registers: group grp owns 8 nodes {grp, grp+8, ..., grp+56}
        float4 accv[8];
        #pragma unroll
        for (int q = 0; q < 8; ++q) {
            int nn = grp + q * 8;
            long long node = nb + nn;
            float4 acc = make_float4(0.f, 0.f, 0.f, 0.f);
            if (node < N) {
                ushort4 rs = xr[node * 32 + lane];
                acc.x = epsv * b2f(rs.x); acc.y = epsv * b2f(rs.y);
                acc.z = epsv * b2f(rs.z); acc.w = epsv * b2f(rs.w);
                int start = ex[nn];
                int deg   = hist[nn];
                int j = 0;
                for (; j + 4 <= deg; j += 4) {
                    int s0 = srt[start + j + 0];
                    int s1 = srt[start + j + 1];
                    int s2 = srt[start + j + 2];
                    int s3 = srt[start + j + 3];
                    ushort4 r0 = xr[(long long)s0 * 32 + lane];
                    ushort4 r1 = xr[(long long)s1 * 32 + lane];
                    ushort4 r2 = xr[(long long)s2 * 32 + lane];
                    ushort4 r3 = xr[(long long)s3 * 32 + lane];
                    acc.x += (b2f(r0.x) + b2f(r1.x)) + (b2f(r2.x) + b2f(r3.x));
                    acc.y += (b2f(r0.y) + b2f(r1.y)) + (b2f(r2.y) + b2f(r3.y));
                    acc.z += (b2f(r0.z) + b2f(r1.z)) + (b2f(r2.z) + b2f(r3.z));
                    acc.w += (b2f(r0.w) + b2f(r1.w)) + (b2f(r2.w) + b2f(r3.w));
                }
                for (; j < deg; ++j) {
                    int sx = srt[start + j];
                    ushort4 r = xr[(long long)sx * 32 + lane];
                    acc.x += b2f(r.x); acc.y += b2f(r.y);
                    acc.z += b2f(r.z); acc.w += b2f(r.w);
                }
            }
            accv[q] = acc;
        }
        __syncthreads();   // all srt reads done; safe to overwrite with S
        #pragma unroll
        for (int q = 0; q < 8; ++q) {
            int nn = grp + q * 8;
            ushort4 o;
            o.x = f2b(accv[q].x); o.y = f2b(accv[q].y);
            o.z = f2b(accv[q].z); o.w = f2b(accv[q].w);
            *(ushort4*)&S[nn * LDH + lane * 4] = o;
        }
        __syncthreads();
    } else {
        // oversized-bucket fallback (statistically never): per-node global scan.
        #pragma unroll
        for (int q = 0; q < 8; ++q) {
            int nn = grp + q * 8;
            long long node = nb + nn;
            float4 acc = make_float4(0.f, 0.f, 0.f, 0.f);
            if (node < N) {
                ushort4 rs = xr[node * 32 + lane];
                acc.x = epsv * b2f(rs.x); acc.y = epsv * b2f(rs.y);
                acc.z = epsv * b2f(rs.z); acc.w = epsv * b2f(rs.w);
                for (int i = 0; i < size; ++i) {
                    uint p = pairs[s + i];
                    if ((int)(p >> PSHIFT) == nn) {
                        long long sx = p & ((1u << PSHIFT) - 1u);
                        ushort4 r = xr[sx * 32 + lane];
                        acc.x += b2f(r.x); acc.y += b2f(r.y);
                        acc.z += b2f(r.z); acc.w += b2f(r.w);
                    }
                }
            }
            ushort4 o;
            o.x = f2b(acc.x); o.y = f2b(acc.y); o.z = f2b(acc.z); o.w = f2b(acc.w);
            *(ushort4*)&S[nn * LDH + lane * 4] = o;
        }
        __syncthreads();
    }
    mlp4(S, w1t, w2t, b1, b2, out, nb, N, tid);
}

extern "C" void kernel_launch(void* const* d_in, const int* in_sizes, int n_in,
                              void* d_out, int out_size, void* d_ws, size_t ws_size,
                              hipStream_t stream) {
    const float* x   = (const float*)d_in[0];
    const void*  ei  = d_in[1];
    const float* eps = (const float*)d_in[3];
    const float* W1  = (const float*)d_in[4];
    const float* b1  = (const float*)d_in[5];
    const float* W2  = (const float*)d_in[6];
    const float* b2  = (const float*)d_in[7];
    float* out = (float*)d_out;

    const int N = in_sizes[0] / D;   // 100000
    const int E = in_sizes[1] / 2;   // 1600000
    const int NC = (N + NPB - 1) / NPB;           // coarse buckets (1563 <= MAXNC)
    const int NCp = (NC + 1 + 255) & ~255;

    // ws: coff[NCp] tot[NCp] harr[NC*NBLK] pairs[E] | xb | w1t w2t
    int* coff   = (int*)d_ws;
    int* tot    = coff + NCp;
    int* harr   = tot + NCp;
    uint* pairs = (uint*)(harr + (size_t)NBLK * NC);
    size_t base   = ((size_t)2 * NCp + (size_t)NBLK * NC + (size_t)E) * sizeof(int);
    size_t xb_off = (base + 15) & ~(size_t)15;
    size_t w1_off = xb_off + (size_t)N * D * sizeof(ushort);
    size_t w2_off = w1_off + (size_t)D * D * sizeof(ushort);
    size_t need   = w2_off + (size_t)D * D * sizeof(ushort);

    if (ws_size < need || NC > MAXNC) return;   // cannot happen for this problem

    ushort* xb  = (ushort*)((char*)d_ws + xb_off);
    ushort* w1t = (ushort*)((char*)d_ws + w1_off);
    ushort* w2t = (ushort*)((char*)d_ws + w2_off);

    const int n8  = N * D / 8;                    // 16-B bf16 store groups
    const int nxb = (n8 + 255) / 256;
    gin_prep<<<NBLK + 128, 256, 0, stream>>>(ei, harr, NC, E, W1, W2, w1t, w2t);
    gin_colsum<<<(NC * 64 + 511) / 512, 512, 0, stream>>>(harr, tot, NC);
    gin_cscatter<<<NBLK + nxb, 256, 0, stream>>>(ei, harr, tot, coff, pairs, NC, E,
                                                 (const float4*)x, (uint4v*)xb, n8);
    gin_sg_mlp<<<NC, 256, 0, stream>>>(pairs, coff, xb, eps, w1t, w2t, b1, b2, out, N);
}

// Round 13
// 124.697 us; speedup vs baseline: 1.2990x; 1.0128x over previous
//
#include <hip/hip_runtime.h>

typedef unsigned int uint;
typedef unsigned short ushort;
typedef __attribute__((ext_vector_type(8))) short short8v;
typedef __attribute__((ext_vector_type(4))) float f32x4;
typedef __attribute__((ext_vector_type(4))) uint uint4v;

#define D 128
#define LDH 136      // LDS row stride in ushorts (272 B, b128-aligned)
#define NPB 64       // nodes per coarse bucket == MLP tile rows (power of 2)
#define PSHIFT 26    // pairs pack: local_dst(6b) << 26 | src(26b)  (needs N < 2^26)
#define NBLK 256     // histogram/scatter blocks (fixed partition)
#define MAXNC 4096   // max coarse buckets (N <= 262144)
#define SRTCAP 4096  // register-staged pairs per block (8 x 512); srt fits S union

// ---------- edge-index dtype hedge (int64 vs int32), wave-uniform ----------
__device__ __forceinline__ bool ei_is64(const int* ei32) {
    return ((ei32[1] | ei32[3] | ei32[5] | ei32[7]) == 0);
}
__device__ __forceinline__ float b2f(ushort u) { return __uint_as_float((uint)u << 16); }
__device__ __forceinline__ ushort f2b(float f) {   // RNE
    uint a = __float_as_uint(f);
    return (ushort)((a + 0x7fffu + ((a >> 16) & 1u)) >> 16);
}
__device__ __forceinline__ uint f2b2(float lo, float hi) {   // pack 2 bf16
    return (uint)f2b(lo) | ((uint)f2b(hi) << 16);
}

// ---- prep: coarse histogram -> TRANSPOSED harr[c][b]  +  W->bf16^T ----
__global__ __launch_bounds__(256) void gin_prep(
    const void* __restrict__ ei_raw, int* __restrict__ harr, int NC, int E,
    const float* __restrict__ W1, const float* __restrict__ W2,
    ushort* __restrict__ w1t, ushort* __restrict__ w2t)
{
    __shared__ int h[MAXNC];
    int bid = blockIdx.x;
    if (bid < NBLK) {
        for (int i = threadIdx.x; i < NC; i += 256) h[i] = 0;
        __syncthreads();
        const int* ei32 = (const int*)ei_raw;
        const long long* ei64 = (const long long*)ei_raw;
        const bool is64 = ei_is64(ei32);
        for (int e = bid * 256 + threadIdx.x; e < E; e += 256 * NBLK) {
            int dst = is64 ? (int)ei64[e] : ei32[e];
            atomicAdd(&h[dst >> 6], 1);   // LDS atomic; NPB == 64
        }
        __syncthreads();
        for (int i = threadIdx.x; i < NC; i += 256)
            harr[(size_t)i * NBLK + bid] = h[i];          // transposed write
    } else {
        int idx = (bid - NBLK) * 256 + threadIdx.x;   // [0, 2*128*128)
        int which = idx >> 14;
        int rem   = idx & 16383;                      // n*128 + k
        int k = rem & 127, n = rem >> 7;
        const float* W = which ? W2 : W1;
        ushort* WT = which ? w2t : w1t;
        WT[rem] = f2b(W[k * D + n]);                  // WT[n][k] = W[k][n]
    }
}

// ---- column scan, one wave per column: harr[c][0..255] -> exclusive; tot[c] ----
__global__ __launch_bounds__(512) void gin_colsum(
    int* __restrict__ harr, int* __restrict__ tot, int NC)
{
    int wv   = (blockIdx.x * 512 + threadIdx.x) >> 6;   // global wave id = column
    int lane = threadIdx.x & 63;
    if (wv >= NC) return;
    int4* col = (int4*)(harr + (size_t)wv * NBLK);
    int4 v = col[lane];                       // coalesced 16 B/lane
    int s = v.x + v.y + v.z + v.w;
    int inc = s;
    #pragma unroll
    for (int d = 1; d < 64; d <<= 1) {
        int t = __shfl_up(inc, d, 64);
        if (lane >= d) inc += t;
    }
    int excl = inc - s;
    int4 o;
    o.x = excl; o.y = excl + v.x; o.z = o.y + v.y; o.w = o.z + v.z;
    col[lane] = o;
    if (lane == 63) tot[wv] = inc;
}

// ---- coarse scatter (blocks < NBLK) + x->bf16 convert (remaining blocks) ----
__global__ __launch_bounds__(256) void gin_cscatter(
    const void* __restrict__ ei_raw, const int* __restrict__ harr,
    const int* __restrict__ tot, int* __restrict__ coff,
    uint* __restrict__ pairs, int NC, int E,
    const float4* __restrict__ x4, uint4v* __restrict__ xb16, int n8)
{
    __shared__ int sc[MAXNC + 1];
    __shared__ int part[256];
    const int tid = threadIdx.x;
    if (blockIdx.x >= NBLK) {            // x -> bf16 conversion (8 floats/thread)
        int i = (blockIdx.x - NBLK) * 256 + tid;
        if (i < n8) {
            float4 a = x4[i * 2 + 0];
            float4 b = x4[i * 2 + 1];
            uint4v o;
            o.x = f2b2(a.x, a.y); o.y = f2b2(a.z, a.w);
            o.z = f2b2(b.x, b.y); o.w = f2b2(b.z, b.w);
            xb16[i] = o;
        }
        return;
    }
    const int CH = (NC + 1 + 255) >> 8;
    const int base = tid * CH;
    int lsum = 0;
    for (int j = 0; j < CH; ++j) {
        int idx = base + j;
        if (idx < NC) lsum += tot[idx];
    }
    part[tid] = lsum;
    __syncthreads();
    for (int d = 1; d < 256; d <<= 1) {
        int t = (tid >= d) ? part[tid - d] : 0;
        __syncthreads();
        part[tid] += t;
        __syncthreads();
    }
    int run = part[tid] - lsum;   // exclusive over chunks
    for (int j = 0; j < CH; ++j) {
        int idx = base + j;
        if (idx <= NC) { sc[idx] = run; if (idx < NC) run += tot[idx]; }
    }
    __syncthreads();
    if (blockIdx.x == 0)
        for (int i = tid; i <= NC; i += 256) coff[i] = sc[i];
    for (int i = tid; i < NC; i += 256)
        sc[i] += harr[(size_t)i * NBLK + blockIdx.x];     // transposed read
    __syncthreads();
    const int* ei32 = (const int*)ei_raw;
    const long long* ei64 = (const long long*)ei_raw;
    const bool is64 = ei_is64(ei32);
    for (int e = blockIdx.x * 256 + tid; e < E; e += 256 * NBLK) {
        int dst, src;
        if (is64) { dst = (int)ei64[e]; src = (int)ei64[E + e]; }
        else      { dst = ei32[e];      src = ei32[E + e]; }
        int c = dst >> 6;
        int p = atomicAdd(&sc[c], 1);   // LDS atomic
        pairs[p] = ((uint)(dst & (NPB - 1)) << PSHIFT) | (uint)src;
    }
}

// ---------------- 8-wave MFMA MLP over S (64 rows), wave w -> n-tile w ----------------
// mfma_f32_16x16x32_bf16: A row=l&15, k=(l>>4)*8+j; B col=l&15; C/D col=l&15,
// row=(l>>4)*4+reg (m89-verified).
__device__ __forceinline__ void mlp8(
    ushort* S, const ushort* __restrict__ w1t, const ushort* __restrict__ w2t,
    const float* __restrict__ b1, const float* __restrict__ b2,
    float* __restrict__ out, long long n0, int N, int tid)
{
    const int w   = tid >> 6;     // wave 0..7 -> output cols [w*16, w*16+16)
    const int l   = tid & 63;
    const int c16 = l & 15;
    const int g   = l >> 4;

    f32x4 acc[4];
    {
        float bv = b1[w * 16 + c16];
        #pragma unroll
        for (int m = 0; m < 4; ++m) acc[m] = (f32x4){bv, bv, bv, bv};
    }
    #pragma unroll
    for (int ks = 0; ks < 4; ++ks) {
        short8v bB = *(const short8v*)&w1t[(w * 16 + c16) * D + ks * 32 + g * 8];
        #pragma unroll
        for (int m = 0; m < 4; ++m) {
            short8v a = *(const short8v*)&S[(m * 16 + c16) * LDH + ks * 32 + g * 8];
            acc[m] = __builtin_amdgcn_mfma_f32_16x16x32_bf16(a, bB, acc[m], 0, 0, 0);
        }
    }
    __syncthreads();   // all Z reads complete before H overwrite
    #pragma unroll
    for (int m = 0; m < 4; ++m)
        #pragma unroll
        for (int r = 0; r < 4; ++r)
            S[(m * 16 + g * 4 + r) * LDH + w * 16 + c16] = f2b(fmaxf(acc[m][r], 0.f));
    __syncthreads();
    {
        float bv = b2[w * 16 + c16];
        #pragma unroll
        for (int m = 0; m < 4; ++m) acc[m] = (f32x4){bv, bv, bv, bv};
    }
    #pragma unroll
    for (int ks = 0; ks < 4; ++ks) {
        short8v bB = *(const short8v*)&w2t[(w * 16 + c16) * D + ks * 32 + g * 8];
        #pragma unroll
        for (int m = 0; m < 4; ++m) {
            short8v a = *(const short8v*)&S[(m * 16 + c16) * LDH + ks * 32 + g * 8];
            acc[m] = __builtin_amdgcn_mfma_f32_16x16x32_bf16(a, bB, acc[m], 0, 0, 0);
        }
    }
    #pragma unroll
    for (int m = 0; m < 4; ++m)
        #pragma unroll
        for (int r = 0; r < 4; ++r) {
            long long row = n0 + m * 16 + g * 4 + r;
            if (row < N)
                __builtin_nontemporal_store(acc[m][r], &out[row * D + w * 16 + c16]);
        }
}

// ---- fused fine-sort + gather(regs) + MFMA MLP: one 512-thread block per bucket ----
// pairs staged in registers (1 nt global read); wave-0 shuffle scan (2 barriers);
// srt and S share one LDS union.
__global__ __launch_bounds__(512, 8) void gin_sg_mlp(
    const uint* __restrict__ pairs, const int* __restrict__ coff,
    const ushort* __restrict__ xb, const float* __restrict__ epsp,
    const ushort* __restrict__ w1t, const ushort* __restrict__ w2t,
    const float* __restrict__ b1, const float* __restrict__ b2,
    float* __restrict__ out, int N)
{
    __shared__ int4 U[(NPB * LDH * 2 + 15) / 16];   // 17408 B union
    int*    srt = (int*)U;                          // [SRTCAP] (16 KB)
    ushort* S   = (ushort*)U;                       // [NPB][LDH]
    __shared__ int hist[NPB], ex[NPB], cur[NPB];
    const int c = blockIdx.x;
    const int s = coff[c], e = coff[c + 1];
    const int size = e - s;
    const int tid = threadIdx.x;
    const float epsv = 1.0f + epsp[0];
    const long long nb = (long long)c * NPB;
    const ushort4* xr = (const ushort4*)xb;
    const int lane = tid & 31, grp = tid >> 5;   // 16 groups of 32 lanes

    if (size <= SRTCAP) {
        if (tid < NPB) { hist[tid] = 0; cur[tid] = 0; }
        uint pr[8]; int np = 0;
        #pragma unroll
        for (int k = 0; k < 8; ++k) {
            int i = tid + k * 512;
            if (i < size) { pr[k] = __builtin_nontemporal_load(&pairs[s + i]); np = k + 1; }
        }
        __syncthreads();
        #pragma unroll
        for (int k = 0; k < 8; ++k)
            if (k < np) atomicAdd(&hist[pr[k] >> PSHIFT], 1);
        __syncthreads();
        if (tid < 64) {                     // single-wave shuffle scan
            int v = hist[tid];
            int inc = v;
            #pragma unroll
            for (int d = 1; d < 64; d <<= 1) {
                int t = __shfl_up(inc, d, 64);
                if (tid >= d) inc += t;
            }
            ex[tid] = inc - v;              // exclusive
        }
        __syncthreads();
        #pragma unroll
        for (int k = 0; k < 8; ++k)
            if (k < np) {
                uint p = pr[k];
                int ld = p >> PSHIFT;
                int pos = atomicAdd(&cur[ld], 1);
                srt[ex[ld] + pos] = (int)(p & ((1u << PSHIFT) - 1u));
            }
        __syncthreads();
        // gather to registers: each group owns 4 nodes {grp, grp+16, grp+32, grp+48}
        float4 accv[4];
        #pragma unroll
        for (int q = 0; q < 4; ++q) {
            int nn = grp + q * 16;
            long long node = nb + nn;
            float4 acc = make_float4(0.f, 0.f, 0.f, 0.f);
            if (node < N) {
                ushort4 rs = xr[node * 32 + lane];
                acc.x = epsv * b2f(rs.x); acc.y = epsv * b2f(rs.y);
                acc.z = epsv * b2f(rs.z); acc.w = epsv * b2f(rs.w);
                int start = ex[nn];
                int deg   = hist[nn];
                int j = 0;
                for (; j + 8 <= deg; j += 8) {
                    int sx[8];
                    #pragma unroll
                    for (int u = 0; u < 8; ++u) sx[u] = srt[start + j + u];
                    ushort4 r[8];
                    #pragma unroll
                    for (int u = 0; u < 8; ++u) r[u] = xr[(long long)sx[u] * 32 + lane];
                    #pragma unroll
                    for (int u = 0; u < 8; ++u) {
                        acc.x += b2f(r[u].x); acc.y += b2f(r[u].y);
                        acc.z += b2f(r[u].z); acc.w += b2f(r[u].w);
                    }
                }
                for (; j < deg; ++j) {
                    int sx = srt[start + j];
                    ushort4 r = xr[(long long)sx * 32 + lane];
                    acc.x += b2f(r.x); acc.y += b2f(r.y);
                    acc.z += b2f(r.z); acc.w += b2f(r.w);
                }
            }
            accv[q] = acc;
        }
        __syncthreads();   // all srt reads done; safe to overwrite with S
        #pragma unroll
        for (int q = 0; q < 4; ++q) {
            int nn = grp + q * 16;
            ushort4 o;
            o.x = f2b(accv[q].x); o.y = f2b(accv[q].y);
            o.z = f2b(accv[q].z); o.w = f2b(accv[q].w);
            *(ushort4*)&S[nn * LDH + lane * 4] = o;
        }
        __syncthreads();
    } else {
        // oversized-bucket fallback (statistically never): per-node global scan.
        #pragma unroll
        for (int q = 0; q < 4; ++q) {
            int nn = grp + q * 16;
            long long node = nb + nn;
            float4 acc = make_float4(0.f, 0.f, 0.f, 0.f);
            if (node < N) {
                ushort4 rs = xr[node * 32 + lane];
                acc.x = epsv * b2f(rs.x); acc.y = epsv * b2f(rs.y);
                acc.z = epsv * b2f(rs.z); acc.w = epsv * b2f(rs.w);
                for (int i = 0; i < size; ++i) {
                    uint p = pairs[s + i];
                    if ((int)(p >> PSHIFT) == nn) {
                        long long sx = p & ((1u << PSHIFT) - 1u);
                        ushort4 r = xr[sx * 32 + lane];
                        acc.x += b2f(r.x); acc.y += b2f(r.y);
                        acc.z += b2f(r.z); acc.w += b2f(r.w);
                    }
                }
            }
            ushort4 o;
            o.x = f2b(acc.x); o.y = f2b(acc.y); o.z = f2b(acc.z); o.w = f2b(acc.w);
            *(ushort4*)&S[nn * LDH + lane * 4] = o;
        }
        __syncthreads();
    }
    mlp8(S, w1t, w2t, b1, b2, out, nb, N, tid);
}

extern "C" void kernel_launch(void* const* d_in, const int* in_sizes, int n_in,
                              void* d_out, int out_size, void* d_ws, size_t ws_size,
                              hipStream_t stream) {
    const float* x   = (const float*)d_in[0];
    const void*  ei  = d_in[1];
    const float* eps = (const float*)d_in[3];
    const float* W1  = (const float*)d_in[4];
    const float* b1  = (const float*)d_in[5];
    const float* W2  = (const float*)d_in[6];
    const float* b2  = (const float*)d_in[7];
    float* out = (float*)d_out;

    const int N = in_sizes[0] / D;   // 100000
    const int E = in_sizes[1] / 2;   // 1600000
    const int NC = (N + NPB - 1) / NPB;           // coarse buckets (1563 <= MAXNC)
    const int NCp = (NC + 1 + 255) & ~255;

    // ws: coff[NCp] tot[NCp] harr[NC*NBLK] pairs[E] | xb | w1t w2t
    int* coff   = (int*)d_ws;
    int* tot    = coff + NCp;
    int* harr   = tot + NCp;
    uint* pairs = (uint*)(harr + (size_t)NBLK * NC);
    size_t base   = ((size_t)2 * NCp + (size_t)NBLK * NC + (size_t)E) * sizeof(int);
    size_t xb_off = (base + 15) & ~(size_t)15;
    size_t w1_off = xb_off + (size_t)N * D * sizeof(ushort);
    size_t w2_off = w1_off + (size_t)D * D * sizeof(ushort);
    size_t need   = w2_off + (size_t)D * D * sizeof(ushort);

    if (ws_size < need || NC > MAXNC) return;   // cannot happen for this problem

    ushort* xb  = (ushort*)((char*)d_ws + xb_off);
    ushort* w1t = (ushort*)((char*)d_ws + w1_off);
    ushort* w2t = (ushort*)((char*)d_ws + w2_off);

    const int n8  = N * D / 8;                    // 16-B bf16 store groups
    const int nxb = (n8 + 255) / 256;
    gin_prep<<<NBLK + 128, 256, 0, stream>>>(ei, harr, NC, E, W1, W2, w1t, w2t);
    gin_colsum<<<(NC * 64 + 511) / 512, 512, 0, stream>>>(harr, tot, NC);
    gin_cscatter<<<NBLK + nxb, 256, 0, stream>>>(ei, harr, tot, coff, pairs, NC, E,
                                                 (const float4*)x, (uint4v*)xb, n8);
    gin_sg_mlp<<<NC, 512, 0, stream>>>(pairs, coff, xb, eps, w1t, w2t, b1, b2, out, N);
}